// Round 3
// baseline (557.834 us; speedup 1.0000x reference)
//
#include <hip/hip_runtime.h>
#include <hip/hip_bf16.h>
#include <cstdint>

using u16 = unsigned short;
using u32 = unsigned int;
using bf16x8 = __attribute__((ext_vector_type(8))) short;
using f32x4  = __attribute__((ext_vector_type(4))) float;

// Problem constants
#define NI 128
#define NC 128
#define RR 36
#define WW 50
#define DD 1024
#define LDC 6400   // = NC*WW
#define ATS 37     // aT row stride (floats): 37 -> lane banks 5w mod 32, conflict-free
#define IMN ((size_t)NI * RR * DD)   // 4,718,592
#define SN  ((size_t)NC * WW * DD)   // 6,553,600

#define GLL16(g, l) __builtin_amdgcn_global_load_lds(                        \
    (const __attribute__((address_space(1))) void*)(g),                      \
    (__attribute__((address_space(3))) void*)(l), 16, 0, 0)

__device__ __forceinline__ float2 bf16pair(u32 u) {
  float2 f;
  f.x = __uint_as_float(u << 16);
  f.y = __uint_as_float(u & 0xffff0000u);
  return f;
}

__device__ __forceinline__ u32 bf16_rne(u32 x) {
  return (x + 0x7FFFu + ((x >> 16) & 1u)) >> 16;
}

// ---------------------------------------------------------------------------
// Kernel 0: dtype sniff (kept for safety; measured: inputs are bf16, flag=0).
// ---------------------------------------------------------------------------
__global__ __launch_bounds__(256) void detect_dtype(const u16* __restrict__ im,
                                                    int* __restrict__ flag) {
  __shared__ int cnt;
  if (threadIdx.x == 0) cnt = 0;
  __syncthreads();
  int local = 0;
#pragma unroll
  for (int v = 0; v < 32; ++v) {
    u16 u = im[threadIdx.x * 32 + v];
    int e = (u >> 7) & 0xFF;
    if (e >= 0xC0) local++;
  }
  atomicAdd(&cnt, local);
  __syncthreads();
  if (threadIdx.x == 0) *flag = (cnt > 8) ? 1 : 0;
}

// ---------------------------------------------------------------------------
// Kernel 0b: canonicalize inputs to bf16.
// ---------------------------------------------------------------------------
__global__ __launch_bounds__(256) void convert_in(const void* __restrict__ im_in,
                                                  const void* __restrict__ s_in,
                                                  u16* __restrict__ imB,
                                                  u16* __restrict__ sB,
                                                  const int* __restrict__ flag) {
  const int f = *flag;
  const size_t TOT8 = (IMN + SN) / 8;
  const size_t stride = (size_t)gridDim.x * blockDim.x;
  for (size_t g = (size_t)blockIdx.x * blockDim.x + threadIdx.x; g < TOT8; g += stride) {
    size_t base = g * 8;
    const void* src;
    u16* dst;
    size_t off;
    if (base < IMN) { src = im_in; dst = imB; off = base; }
    else            { src = s_in;  dst = sB;  off = base - IMN; }
    if (f) {
      const u32* sp = (const u32*)src + off;
      u16 o[8];
#pragma unroll
      for (int e = 0; e < 8; ++e) o[e] = (u16)bf16_rne(sp[e]);
      *(uint4*)(dst + off) = *(const uint4*)o;
    } else {
      *(uint4*)(dst + off) = *(const uint4*)((const u16*)src + off);
    }
  }
}

// ---------------------------------------------------------------------------
// Kernel 0c: caption word norms. One wave per (c,w) row of 1024 bf16.
// ---------------------------------------------------------------------------
__global__ __launch_bounds__(64) void w1_k(const u16* __restrict__ s,
                                           float* __restrict__ w1) {
  const int cw = blockIdx.x;           // 0..6399
  const int lane = threadIdx.x;
  const u16* sp = s + (size_t)cw * DD + lane * 16;
  uint4 A0 = *(const uint4*)sp;
  uint4 A1 = *(const uint4*)(sp + 8);
  float sum = 0.f;
  u32 uu[8] = {A0.x, A0.y, A0.z, A0.w, A1.x, A1.y, A1.z, A1.w};
#pragma unroll
  for (int e = 0; e < 8; ++e) {
    float2 f = bf16pair(uu[e]);
    sum += f.x * f.x + f.y * f.y;
  }
#pragma unroll
  for (int off = 32; off > 0; off >>= 1) sum += __shfl_down(sum, off);
  if (lane == 0) w1[cw] = sqrtf(sum);
}

// ---------------------------------------------------------------------------
// Kernel 1: per-image Gram G[i][r][r'] = <im[i,r], im[i,r']>. All 4 waves
// MFMA (K split 4-way), LDS cross-wave reduce at the end.
// ---------------------------------------------------------------------------
__global__ __launch_bounds__(256) void gram_k(const u16* __restrict__ im,
                                              float* __restrict__ G) {
  __shared__ u16 ims[48 * 520];        // 49,920 B; reused as float scratch later
  const int b = blockIdx.x;
  const int t = threadIdx.x;
  const int lane = t & 63, wv = t >> 6;
  const int lm = lane & 15, q = lane >> 4;
  f32x4 acc[3][3] = {};

  for (int p = 0; p < 2; ++p) {
    const int kk = p * 512;
#pragma unroll
    for (int v = 0; v < 9; ++v) {
      int u = t + v * 256;          // 0..2303 = 36*64
      int row = u >> 6;
      int kloc = (u & 63) * 8;
      uint4 val = *(const uint4*)(im + (size_t)b * (RR * DD) + (size_t)row * DD + kk + kloc);
      *(uint4*)&ims[row * 520 + kloc] = val;
    }
    if (p == 0) {
#pragma unroll
      for (int v = 0; v < 4; ++v) {
        int u = t + v * 256;
        if (u < 780) {              // 12*520/8 = 780 uint4
          uint4 z; z.x = 0; z.y = 0; z.z = 0; z.w = 0;
          *(uint4*)&ims[36 * 520 + u * 8] = z;
        }
      }
    }
    __syncthreads();
    // wave wv handles ks = wv*4 .. wv*4+3
#pragma unroll
    for (int kq = 0; kq < 4; ++kq) {
      const int ks = wv * 4 + kq;
      bf16x8 af[3];
#pragma unroll
      for (int mi = 0; mi < 3; ++mi)
        af[mi] = *(const bf16x8*)&ims[(mi * 16 + lm) * 520 + ks * 32 + q * 8];
#pragma unroll
      for (int mi = 0; mi < 3; ++mi)
#pragma unroll
        for (int ni = 0; ni < 3; ++ni)
          acc[mi][ni] = __builtin_amdgcn_mfma_f32_16x16x32_bf16(af[mi], af[ni], acc[mi][ni], 0, 0, 0);
    }
    __syncthreads();
  }
  // cross-wave reduce in LDS (reuse ims as float scratch: 3*48*48*4 = 27,648 B)
  float* red = (float*)ims;
  if (wv > 0) {
#pragma unroll
    for (int mi = 0; mi < 3; ++mi)
#pragma unroll
      for (int ni = 0; ni < 3; ++ni)
#pragma unroll
        for (int v = 0; v < 4; ++v) {
          int row = mi * 16 + q * 4 + v;
          int col = ni * 16 + lm;
          red[(wv - 1) * 2304 + row * 48 + col] = acc[mi][ni][v];
        }
  }
  __syncthreads();
  if (wv == 0) {
#pragma unroll
    for (int mi = 0; mi < 3; ++mi)
#pragma unroll
      for (int ni = 0; ni < 3; ++ni)
#pragma unroll
        for (int v = 0; v < 4; ++v) {
          int row = mi * 16 + q * 4 + v;
          int col = ni * 16 + lm;
          float r0 = acc[mi][ni][v] + red[row * 48 + col] +
                     red[2304 + row * 48 + col] + red[4608 + row * 48 + col];
          if (row < RR && col < RR)
            G[(size_t)b * (RR * RR) + row * RR + col] = r0;
        }
  }
}

// ---------------------------------------------------------------------------
// Kernel 2: raw[ir][cw] = sum_k im[ir][k] * s[cw][k]    (bf16 MFMA, f32 out)
// M=4608, N=6400, K=1024. BM=BN=128, BK=32. grid (50, 36), 256 threads.
// ---------------------------------------------------------------------------
__global__ __launch_bounds__(256) void gemm_raw(const u16* __restrict__ A,
                                                const u16* __restrict__ B,
                                                float* __restrict__ C) {
  __shared__ u16 As[128 * 32];
  __shared__ u16 Bs[128 * 32];
  const int t = threadIdx.x;
  const int col0 = blockIdx.x * 128;
  const int row0 = blockIdx.y * 128;
  const int lane = t & 63, wv = t >> 6;
  const int wm = wv >> 1, wn = wv & 1;
  const int lm = lane & 15, q = lane >> 4;
  f32x4 acc[4][4] = {};

  const int u0 = t, u1 = t + 256;
  const u16* a0 = A + (size_t)(row0 + (u0 >> 2)) * DD + (u0 & 3) * 8;
  const u16* a1 = A + (size_t)(row0 + (u1 >> 2)) * DD + (u1 & 3) * 8;
  const u16* b0 = B + (size_t)(col0 + (u0 >> 2)) * DD + (u0 & 3) * 8;
  const u16* b1 = B + (size_t)(col0 + (u1 >> 2)) * DD + (u1 & 3) * 8;

  for (int k0 = 0; k0 < DD; k0 += 32) {
    GLL16(a0 + k0, &As[u0 * 8]);
    GLL16(a1 + k0, &As[u1 * 8]);
    GLL16(b0 + k0, &Bs[u0 * 8]);
    GLL16(b1 + k0, &Bs[u1 * 8]);
    __syncthreads();
    bf16x8 af[4], bf[4];
#pragma unroll
    for (int mi = 0; mi < 4; ++mi)
      af[mi] = *(const bf16x8*)&As[(wm * 64 + mi * 16 + lm) * 32 + q * 8];
#pragma unroll
    for (int ni = 0; ni < 4; ++ni)
      bf[ni] = *(const bf16x8*)&Bs[(wn * 64 + ni * 16 + lm) * 32 + q * 8];
#pragma unroll
    for (int mi = 0; mi < 4; ++mi)
#pragma unroll
      for (int ni = 0; ni < 4; ++ni)
        acc[mi][ni] = __builtin_amdgcn_mfma_f32_16x16x32_bf16(af[mi], bf[ni], acc[mi][ni], 0, 0, 0);
    __syncthreads();
  }
#pragma unroll
  for (int mi = 0; mi < 4; ++mi)
#pragma unroll
    for (int ni = 0; ni < 4; ++ni)
#pragma unroll
      for (int v = 0; v < 4; ++v) {
        int rr = row0 + wm * 64 + mi * 16 + q * 4 + v;
        int cc = col0 + wn * 64 + ni * 16 + lm;
        C[(size_t)rr * LDC + cc] = acc[mi][ni][v];
      }
}

// ---------------------------------------------------------------------------
// Kernel 3: postproc, wave-per-(c,i)-pair. Block = (i, 4 captions), 4 waves.
// Phase 1 (lanes=r): load raw row, leaky+mask, l2-norm over w, write aT
// transposed (stride 37 -> conflict-free). One barrier. Phase 2-4 (lanes=w):
// softmax over r with e in registers, w12 via inverse-leaky recovery,
// q = e'Ge with G broadcast from LDS, LSE via shuffle reduce.
// ---------------------------------------------------------------------------
__global__ __launch_bounds__(256, 4) void postproc(const float* __restrict__ raw,
                                                   const float* __restrict__ G,
                                                   const float* __restrict__ w1,
                                                   const int* __restrict__ s_l,
                                                   float* __restrict__ scores) {
  const int i = blockIdx.y;
  const int c = blockIdx.x * 4 + (threadIdx.x >> 6);
  const int lane = threadIdx.x & 63;
  const int wv = threadIdx.x >> 6;
  __shared__ float G_s[RR * RR];            // 5184 B (broadcast reads only)
  __shared__ float aT[4][WW * ATS];         // 4 * 7400 B
  __shared__ float rnrm_s[4][RR];           // 576 B

  for (int idx = threadIdx.x; idx < RR * RR; idx += 256)
    G_s[idx] = G[(size_t)i * (RR * RR) + idx];
  const int L = s_l[c];

  // ---- phase 1: lanes = regions ----
  if (lane < RR) {
    const float* rp = raw + (size_t)(i * RR + lane) * LDC + c * WW;
    float x[WW];
#pragma unroll
    for (int j = 0; j < 25; ++j) {
      float2 v = ((const float2*)rp)[j];
      x[2 * j] = v.x; x[2 * j + 1] = v.y;
    }
    float sum = 0.f;
#pragma unroll
    for (int w = 0; w < WW; ++w) {
      float xv = x[w];
      xv = xv > 0.f ? xv : 0.1f * xv;
      if (w >= L) xv = 0.f;
      x[w] = xv;
      sum += xv * xv;
    }
    float sq = sqrtf(sum) + 1e-8f;
    float nrm9 = 9.0f / sq;
    rnrm_s[wv][lane] = sq * (1.0f / 9.0f);
#pragma unroll
    for (int w = 0; w < WW; ++w)
      aT[wv][w * ATS + lane] = x[w] * nrm9;
  }
  __syncthreads();

  // ---- phases 2-4: lanes = words ----
  float ew = 0.f;
  if (lane < WW) {
    const float* row = &aT[wv][lane * ATS];
    float m = row[0];
#pragma unroll
    for (int r = 1; r < RR; ++r) m = fmaxf(m, row[r]);
    float e[RR];
    float sum = 0.f, w12r = 0.f;
#pragma unroll
    for (int r = 0; r < RR; ++r) {
      float a = row[r];
      float er = __expf(a - m);
      e[r] = er;
      sum += er;
      float rawv = (a > 0.f ? a : 10.0f * a) * rnrm_s[wv][r];
      w12r += er * rawv;
    }
    float inv = 1.0f / sum;
    float qq = 0.f;
#pragma unroll
    for (int r = 0; r < RR; ++r) {
      float h = 0.f;
#pragma unroll
      for (int j = 0; j < 9; ++j) {
        f32x4 g = *(const f32x4*)&G_s[r * RR + j * 4];
        h += g[0] * e[4 * j] + g[1] * e[4 * j + 1] +
             g[2] * e[4 * j + 2] + g[3] * e[4 * j + 3];
      }
      qq += e[r] * h;
    }
    float w2 = sqrtf(fmaxf(qq, 0.f)) * inv;
    float w12 = w12r * inv;
    float w1v = w1[c * WW + lane];
    float rs = w12 / fmaxf(w1v * w2, 1e-8f);
    ew = (lane < L) ? __expf(6.0f * rs) : 0.f;
  }
#pragma unroll
  for (int off = 32; off > 0; off >>= 1) ew += __shfl_down(ew, off);
  if (lane == 0) scores[i * NC + c] = logf(ew) * (1.0f / 6.0f);
}

// ---------------------------------------------------------------------------
// Kernel 4: hardest-negative contrastive loss over scores (128x128).
// ---------------------------------------------------------------------------
__global__ __launch_bounds__(128) void loss_k(const float* __restrict__ scores,
                                              u32* __restrict__ out) {
  __shared__ float diag[NI];
  __shared__ float red[NI];
  const int t = threadIdx.x;
  diag[t] = scores[t * NC + t];
  __syncthreads();
  const float di = diag[t];
  float rowmax = 0.f, colmax = 0.f;
  for (int k = 0; k < NC; ++k) {
    if (k != t) {
      float sr = scores[t * NC + k];
      rowmax = fmaxf(rowmax, fmaxf(0.2f + sr - di, 0.f));
      float sc = scores[k * NC + t];
      colmax = fmaxf(colmax, fmaxf(0.2f + sc - di, 0.f));
    }
  }
  red[t] = rowmax + colmax;
  __syncthreads();
  for (int st = 64; st > 0; st >>= 1) {
    if (t < st) red[t] += red[t + st];
    __syncthreads();
  }
  if (t == 0) {
    u32 b = bf16_rne(__float_as_uint(red[0]));
    out[0] = b | (b << 16);
  }
}

// ---------------------------------------------------------------------------
extern "C" void kernel_launch(void* const* d_in, const int* in_sizes, int n_in,
                              void* d_out, int out_size, void* d_ws, size_t ws_size,
                              hipStream_t stream) {
  const void* im_in = d_in[0];
  const void* s_in  = d_in[1];
  const int*  sl    = (const int*)d_in[2];

  char* ws = (char*)d_ws;
  u16*   imB    = (u16*)ws;                                  // 9,437,184 B
  u16*   sB     = (u16*)(ws + 9437184);                      // 13,107,200 B
  float* raw    = (float*)(ws + 22544384);                   // 117,964,800 B
  float* G      = (float*)(ws + 22544384 + 117964800);       // 663,552 B
  float* w1     = G + 128 * RR * RR;                         // 25,600 B
  float* scores = w1 + NC * WW;                              // 65,536 B
  int*   flag   = (int*)(scores + NI * NC);

  detect_dtype<<<dim3(1), dim3(256), 0, stream>>>((const u16*)im_in, flag);
  convert_in<<<dim3(2048), dim3(256), 0, stream>>>(im_in, s_in, imB, sB, flag);
  w1_k<<<dim3(NC * WW), dim3(64), 0, stream>>>(sB, w1);
  gram_k<<<dim3(128), dim3(256), 0, stream>>>(imB, G);
  gemm_raw<<<dim3(50, 36), dim3(256), 0, stream>>>(imB, sB, raw);
  postproc<<<dim3(32, 128), dim3(256), 0, stream>>>(raw, G, w1, sl, scores);
  loss_k<<<dim3(1), dim3(128), 0, stream>>>(scores, (u32*)d_out);
}

// Round 4
// 378.450 us; speedup vs baseline: 1.4740x; 1.4740x over previous
//
#include <hip/hip_runtime.h>
#include <hip/hip_bf16.h>
#include <cstdint>

using u16 = unsigned short;
using u32 = unsigned int;
using bf16x8 = __attribute__((ext_vector_type(8))) short;
using f32x4  = __attribute__((ext_vector_type(4))) float;

// Problem constants
#define NI 128
#define NC 128
#define RR 36
#define WW 50
#define DD 1024
#define LDC 6400   // = NC*WW
#define ATS 37     // aT row stride (floats): bank = (5*lane + w) % 32, conflict-free
#define IMN ((size_t)NI * RR * DD)   // 4,718,592
#define SN  ((size_t)NC * WW * DD)   // 6,553,600

#define GLL16(g, l) __builtin_amdgcn_global_load_lds(                        \
    (const __attribute__((address_space(1))) void*)(g),                      \
    (__attribute__((address_space(3))) void*)(l), 16, 0, 0)

__device__ __forceinline__ float2 bf16pair(u32 u) {
  float2 f;
  f.x = __uint_as_float(u << 16);
  f.y = __uint_as_float(u & 0xffff0000u);
  return f;
}

__device__ __forceinline__ u32 bf16_rne(u32 x) {
  return (x + 0x7FFFu + ((x >> 16) & 1u)) >> 16;
}

// ---------------------------------------------------------------------------
// Kernel 0: dtype sniff (measured: inputs are bf16, flag=0; kept for safety).
// ---------------------------------------------------------------------------
__global__ __launch_bounds__(256) void detect_dtype(const u16* __restrict__ im,
                                                    int* __restrict__ flag) {
  __shared__ int cnt;
  if (threadIdx.x == 0) cnt = 0;
  __syncthreads();
  int local = 0;
#pragma unroll
  for (int v = 0; v < 32; ++v) {
    u16 u = im[threadIdx.x * 32 + v];
    int e = (u >> 7) & 0xFF;
    if (e >= 0xC0) local++;
  }
  atomicAdd(&cnt, local);
  __syncthreads();
  if (threadIdx.x == 0) *flag = (cnt > 8) ? 1 : 0;
}

// ---------------------------------------------------------------------------
// Kernel 0b: canonicalize inputs to bf16.
// ---------------------------------------------------------------------------
__global__ __launch_bounds__(256) void convert_in(const void* __restrict__ im_in,
                                                  const void* __restrict__ s_in,
                                                  u16* __restrict__ imB,
                                                  u16* __restrict__ sB,
                                                  const int* __restrict__ flag) {
  const int f = *flag;
  const size_t TOT8 = (IMN + SN) / 8;
  const size_t stride = (size_t)gridDim.x * blockDim.x;
  for (size_t g = (size_t)blockIdx.x * blockDim.x + threadIdx.x; g < TOT8; g += stride) {
    size_t base = g * 8;
    const void* src;
    u16* dst;
    size_t off;
    if (base < IMN) { src = im_in; dst = imB; off = base; }
    else            { src = s_in;  dst = sB;  off = base - IMN; }
    if (f) {
      const u32* sp = (const u32*)src + off;
      u16 o[8];
#pragma unroll
      for (int e = 0; e < 8; ++e) o[e] = (u16)bf16_rne(sp[e]);
      *(uint4*)(dst + off) = *(const uint4*)o;
    } else {
      *(uint4*)(dst + off) = *(const uint4*)((const u16*)src + off);
    }
  }
}

// ---------------------------------------------------------------------------
// Kernel 0c: caption word norms. One wave per (c,w) row of 1024 bf16.
// ---------------------------------------------------------------------------
__global__ __launch_bounds__(64) void w1_k(const u16* __restrict__ s,
                                           float* __restrict__ w1) {
  const int cw = blockIdx.x;           // 0..6399
  const int lane = threadIdx.x;
  const u16* sp = s + (size_t)cw * DD + lane * 16;
  uint4 A0 = *(const uint4*)sp;
  uint4 A1 = *(const uint4*)(sp + 8);
  float sum = 0.f;
  u32 uu[8] = {A0.x, A0.y, A0.z, A0.w, A1.x, A1.y, A1.z, A1.w};
#pragma unroll
  for (int e = 0; e < 8; ++e) {
    float2 f = bf16pair(uu[e]);
    sum += f.x * f.x + f.y * f.y;
  }
#pragma unroll
  for (int off = 32; off > 0; off >>= 1) sum += __shfl_down(sum, off);
  if (lane == 0) w1[cw] = sqrtf(sum);
}

// ---------------------------------------------------------------------------
// Kernel 1: per-image Gram G[i][r][r'] = <im[i,r], im[i,r']>. All 4 waves
// MFMA (K split 4-way), LDS cross-wave reduce at the end.
// ---------------------------------------------------------------------------
__global__ __launch_bounds__(256) void gram_k(const u16* __restrict__ im,
                                              float* __restrict__ G) {
  __shared__ u16 ims[48 * 520];        // 49,920 B; reused as float scratch later
  const int b = blockIdx.x;
  const int t = threadIdx.x;
  const int lane = t & 63, wv = t >> 6;
  const int lm = lane & 15, q = lane >> 4;
  f32x4 acc[3][3] = {};

  for (int p = 0; p < 2; ++p) {
    const int kk = p * 512;
#pragma unroll
    for (int v = 0; v < 9; ++v) {
      int u = t + v * 256;          // 0..2303 = 36*64
      int row = u >> 6;
      int kloc = (u & 63) * 8;
      uint4 val = *(const uint4*)(im + (size_t)b * (RR * DD) + (size_t)row * DD + kk + kloc);
      *(uint4*)&ims[row * 520 + kloc] = val;
    }
    if (p == 0) {
#pragma unroll
      for (int v = 0; v < 4; ++v) {
        int u = t + v * 256;
        if (u < 780) {              // 12*520/8 = 780 uint4
          uint4 z; z.x = 0; z.y = 0; z.z = 0; z.w = 0;
          *(uint4*)&ims[36 * 520 + u * 8] = z;
        }
      }
    }
    __syncthreads();
#pragma unroll
    for (int kq = 0; kq < 4; ++kq) {
      const int ks = wv * 4 + kq;
      bf16x8 af[3];
#pragma unroll
      for (int mi = 0; mi < 3; ++mi)
        af[mi] = *(const bf16x8*)&ims[(mi * 16 + lm) * 520 + ks * 32 + q * 8];
#pragma unroll
      for (int mi = 0; mi < 3; ++mi)
#pragma unroll
        for (int ni = 0; ni < 3; ++ni)
          acc[mi][ni] = __builtin_amdgcn_mfma_f32_16x16x32_bf16(af[mi], af[ni], acc[mi][ni], 0, 0, 0);
    }
    __syncthreads();
  }
  float* red = (float*)ims;
  if (wv > 0) {
#pragma unroll
    for (int mi = 0; mi < 3; ++mi)
#pragma unroll
      for (int ni = 0; ni < 3; ++ni)
#pragma unroll
        for (int v = 0; v < 4; ++v) {
          int row = mi * 16 + q * 4 + v;
          int col = ni * 16 + lm;
          red[(wv - 1) * 2304 + row * 48 + col] = acc[mi][ni][v];
        }
  }
  __syncthreads();
  if (wv == 0) {
#pragma unroll
    for (int mi = 0; mi < 3; ++mi)
#pragma unroll
      for (int ni = 0; ni < 3; ++ni)
#pragma unroll
        for (int v = 0; v < 4; ++v) {
          int row = mi * 16 + q * 4 + v;
          int col = ni * 16 + lm;
          float r0 = acc[mi][ni][v] + red[row * 48 + col] +
                     red[2304 + row * 48 + col] + red[4608 + row * 48 + col];
          if (row < RR && col < RR)
            G[(size_t)b * (RR * RR) + row * RR + col] = r0;
        }
  }
}

// ---------------------------------------------------------------------------
// Kernel 2: raw[ir][cw] = sum_k im[ir][k] * s[cw][k]  (bf16 MFMA, bf16 out)
// M=4608, N=6400, K=1024. BM=BN=128, BK=32. grid (50, 36), 256 threads.
// ---------------------------------------------------------------------------
__global__ __launch_bounds__(256) void gemm_raw(const u16* __restrict__ A,
                                                const u16* __restrict__ B,
                                                u16* __restrict__ C) {
  __shared__ u16 As[128 * 32];
  __shared__ u16 Bs[128 * 32];
  const int t = threadIdx.x;
  const int col0 = blockIdx.x * 128;
  const int row0 = blockIdx.y * 128;
  const int lane = t & 63, wv = t >> 6;
  const int wm = wv >> 1, wn = wv & 1;
  const int lm = lane & 15, q = lane >> 4;
  f32x4 acc[4][4] = {};

  const int u0 = t, u1 = t + 256;
  const u16* a0 = A + (size_t)(row0 + (u0 >> 2)) * DD + (u0 & 3) * 8;
  const u16* a1 = A + (size_t)(row0 + (u1 >> 2)) * DD + (u1 & 3) * 8;
  const u16* b0 = B + (size_t)(col0 + (u0 >> 2)) * DD + (u0 & 3) * 8;
  const u16* b1 = B + (size_t)(col0 + (u1 >> 2)) * DD + (u1 & 3) * 8;

  for (int k0 = 0; k0 < DD; k0 += 32) {
    GLL16(a0 + k0, &As[u0 * 8]);
    GLL16(a1 + k0, &As[u1 * 8]);
    GLL16(b0 + k0, &Bs[u0 * 8]);
    GLL16(b1 + k0, &Bs[u1 * 8]);
    __syncthreads();
    bf16x8 af[4], bf[4];
#pragma unroll
    for (int mi = 0; mi < 4; ++mi)
      af[mi] = *(const bf16x8*)&As[(wm * 64 + mi * 16 + lm) * 32 + q * 8];
#pragma unroll
    for (int ni = 0; ni < 4; ++ni)
      bf[ni] = *(const bf16x8*)&Bs[(wn * 64 + ni * 16 + lm) * 32 + q * 8];
#pragma unroll
    for (int mi = 0; mi < 4; ++mi)
#pragma unroll
      for (int ni = 0; ni < 4; ++ni)
        acc[mi][ni] = __builtin_amdgcn_mfma_f32_16x16x32_bf16(af[mi], bf[ni], acc[mi][ni], 0, 0, 0);
    __syncthreads();
  }
#pragma unroll
  for (int mi = 0; mi < 4; ++mi)
#pragma unroll
    for (int ni = 0; ni < 4; ++ni)
#pragma unroll
      for (int v = 0; v < 4; ++v) {
        int rr = row0 + wm * 64 + mi * 16 + q * 4 + v;
        int cc = col0 + wn * 64 + ni * 16 + lm;
        C[(size_t)rr * LDC + cc] = (u16)bf16_rne(__float_as_uint(acc[mi][ni][v]));
      }
}

// ---------------------------------------------------------------------------
// Kernel 3: postproc, wave-per-(c,i) pair, spill-free.
// Phase 1 (lanes=r): load bf16 raw row, leaky+mask, write to aT (stride 37),
// accumulate norm, then rescale aT in-place (no x[50] register array).
// Phase 2-4: UNIFORM control flow for all 64 lanes (lanes>=50 clamped, masked
// by lane<L at the end) so G reads are wave-uniform -> scalar s_load path.
// e[36]/a[36] fully-unrolled register arrays; launch_bounds(256,2) => no cap
// at 64 VGPRs, no scratch spill.
// ---------------------------------------------------------------------------
__global__ __launch_bounds__(256, 2) void postproc(const u16* __restrict__ raw,
                                                   const float* __restrict__ G,
                                                   const float* __restrict__ w1,
                                                   const int* __restrict__ s_l,
                                                   float* __restrict__ scores) {
  const int i = blockIdx.y;
  const int wv = threadIdx.x >> 6;
  const int c = blockIdx.x * 4 + wv;
  const int lane = threadIdx.x & 63;
  __shared__ float aT[4][WW * ATS];         // 4 * 7400 B
  __shared__ float rnrm_s[4][RR];           // 576 B
  const int L = s_l[c];

  // ---- phase 1: lanes = regions ----
  if (lane < RR) {
    const u16* rp = raw + (size_t)(i * RR + lane) * LDC + c * WW;
    float sum = 0.f;
#pragma unroll
    for (int j = 0; j < 25; ++j) {
      float2 v = bf16pair(((const u32*)rp)[j]);
      float x0 = v.x > 0.f ? v.x : 0.1f * v.x;
      float x1 = v.y > 0.f ? v.y : 0.1f * v.y;
      if (2 * j     >= L) x0 = 0.f;
      if (2 * j + 1 >= L) x1 = 0.f;
      aT[wv][(2 * j) * ATS + lane]     = x0;
      aT[wv][(2 * j + 1) * ATS + lane] = x1;
      sum += x0 * x0 + x1 * x1;
    }
    float sq = sqrtf(sum) + 1e-8f;
    float nrm9 = 9.0f / sq;
    rnrm_s[wv][lane] = sq * (1.0f / 9.0f);
#pragma unroll
    for (int w = 0; w < WW; ++w)
      aT[wv][w * ATS + lane] *= nrm9;
  }
  __syncthreads();

  // ---- phases 2-4: uniform flow, lanes = words (clamped) ----
  const int wIdx = lane < WW ? lane : WW - 1;
  const float* row = &aT[wv][wIdx * ATS];
  float a[RR];
  float m = -1e30f;
#pragma unroll
  for (int r = 0; r < RR; ++r) {
    a[r] = row[r];
    m = fmaxf(m, a[r]);
  }
  float e[RR];
  float sum = 0.f, w12r = 0.f;
#pragma unroll
  for (int r = 0; r < RR; ++r) {
    float er = __expf(a[r] - m);
    e[r] = er;
    sum += er;
    float rawv = (a[r] > 0.f ? a[r] : 10.0f * a[r]) * rnrm_s[wv][r];
    w12r += er * rawv;
  }
  const float* Gp = G + (size_t)i * (RR * RR);
  float qq = 0.f;
#pragma unroll
  for (int r = 0; r < RR; ++r) {
    float h = 0.f;
#pragma unroll
    for (int j = 0; j < RR; ++j)
      h += Gp[r * RR + j] * e[j];
    qq += e[r] * h;
  }
  // rs = (w12r/sum) / max(w1 * sqrt(qq)/sum, eps)  ==  w12r / max(w1*sqrt(qq), eps*sum)
  float w1v = w1[c * WW + wIdx];
  float denom = fmaxf(w1v * sqrtf(fmaxf(qq, 0.f)), 1e-8f * sum);
  float rs = w12r / denom;
  float ew = (lane < L) ? __expf(6.0f * rs) : 0.f;
#pragma unroll
  for (int off = 32; off > 0; off >>= 1) ew += __shfl_down(ew, off);
  if (lane == 0) scores[i * NC + c] = logf(ew) * (1.0f / 6.0f);
}

// ---------------------------------------------------------------------------
// Kernel 4: hardest-negative contrastive loss over scores (128x128).
// ---------------------------------------------------------------------------
__global__ __launch_bounds__(128) void loss_k(const float* __restrict__ scores,
                                              u32* __restrict__ out) {
  __shared__ float diag[NI];
  __shared__ float red[NI];
  const int t = threadIdx.x;
  diag[t] = scores[t * NC + t];
  __syncthreads();
  const float di = diag[t];
  float rowmax = 0.f, colmax = 0.f;
  for (int k = 0; k < NC; ++k) {
    if (k != t) {
      float sr = scores[t * NC + k];
      rowmax = fmaxf(rowmax, fmaxf(0.2f + sr - di, 0.f));
      float sc = scores[k * NC + t];
      colmax = fmaxf(colmax, fmaxf(0.2f + sc - di, 0.f));
    }
  }
  red[t] = rowmax + colmax;
  __syncthreads();
  for (int st = 64; st > 0; st >>= 1) {
    if (t < st) red[t] += red[t + st];
    __syncthreads();
  }
  if (t == 0) {
    u32 b = bf16_rne(__float_as_uint(red[0]));
    out[0] = b | (b << 16);
  }
}

// ---------------------------------------------------------------------------
extern "C" void kernel_launch(void* const* d_in, const int* in_sizes, int n_in,
                              void* d_out, int out_size, void* d_ws, size_t ws_size,
                              hipStream_t stream) {
  const void* im_in = d_in[0];
  const void* s_in  = d_in[1];
  const int*  sl    = (const int*)d_in[2];

  char* ws = (char*)d_ws;
  u16*   imB    = (u16*)ws;                                  //  9,437,184 B
  u16*   sB     = (u16*)(ws + 9437184);                      // 13,107,200 B
  u16*   raw    = (u16*)(ws + 22544384);                     // 58,982,400 B (bf16)
  float* G      = (float*)(ws + 22544384 + 58982400);        //    663,552 B
  float* w1     = G + 128 * RR * RR;                         //     25,600 B
  float* scores = w1 + NC * WW;                              //     65,536 B
  int*   flag   = (int*)(scores + NI * NC);

  detect_dtype<<<dim3(1), dim3(256), 0, stream>>>((const u16*)im_in, flag);
  convert_in<<<dim3(2048), dim3(256), 0, stream>>>(im_in, s_in, imB, sB, flag);
  w1_k<<<dim3(NC * WW), dim3(64), 0, stream>>>(sB, w1);
  gram_k<<<dim3(128), dim3(256), 0, stream>>>(imB, G);
  gemm_raw<<<dim3(50, 36), dim3(256), 0, stream>>>(imB, sB, raw);
  postproc<<<dim3(32, 128), dim3(256), 0, stream>>>(raw, G, w1, sl, scores);
  loss_k<<<dim3(1), dim3(128), 0, stream>>>(scores, (u32*)d_out);
}

// Round 5
// 285.063 us; speedup vs baseline: 1.9569x; 1.3276x over previous
//
#include <hip/hip_runtime.h>
#include <hip/hip_bf16.h>
#include <cstdint>

using u16 = unsigned short;
using u32 = unsigned int;
using bf16x8 = __attribute__((ext_vector_type(8))) short;
using f32x4  = __attribute__((ext_vector_type(4))) float;

// Problem constants
#define NI 128
#define NC 128
#define RR 36
#define WW 50
#define DD 1024
#define LDC 6400   // = NC*WW
#define ATS 37     // aT row stride (floats): bank = (5*w + r) % 32, conflict-free
#define IMN ((size_t)NI * RR * DD)   // 4,718,592
#define SN  ((size_t)NC * WW * DD)   // 6,553,600

#define GLL16(g, l) __builtin_amdgcn_global_load_lds(                        \
    (const __attribute__((address_space(1))) void*)(g),                      \
    (__attribute__((address_space(3))) void*)(l), 16, 0, 0)

// constant-address-space float: uniform loads select s_load (SGPR data)
typedef const __attribute__((address_space(4))) float cfloat;

__device__ __forceinline__ float2 bf16pair(u32 u) {
  float2 f;
  f.x = __uint_as_float(u << 16);
  f.y = __uint_as_float(u & 0xffff0000u);
  return f;
}

__device__ __forceinline__ u32 bf16_rne(u32 x) {
  return (x + 0x7FFFu + ((x >> 16) & 1u)) >> 16;
}

// ---------------------------------------------------------------------------
// Kernel 0: dtype sniff (measured: inputs are bf16, flag=0; kept for safety).
// ---------------------------------------------------------------------------
__global__ __launch_bounds__(256) void detect_dtype(const u16* __restrict__ im,
                                                    int* __restrict__ flag) {
  __shared__ int cnt;
  if (threadIdx.x == 0) cnt = 0;
  __syncthreads();
  int local = 0;
#pragma unroll
  for (int v = 0; v < 32; ++v) {
    u16 u = im[threadIdx.x * 32 + v];
    int e = (u >> 7) & 0xFF;
    if (e >= 0xC0) local++;
  }
  atomicAdd(&cnt, local);
  __syncthreads();
  if (threadIdx.x == 0) *flag = (cnt > 8) ? 1 : 0;
}

// ---------------------------------------------------------------------------
// Kernel 0b: fp32 -> bf16 conversion. Early-exit when inputs already bf16
// (flag==0): consumers then read the original input pointers directly.
// ---------------------------------------------------------------------------
__global__ __launch_bounds__(256) void convert_in(const void* __restrict__ im_in,
                                                  const void* __restrict__ s_in,
                                                  u16* __restrict__ imB,
                                                  u16* __restrict__ sB,
                                                  const int* __restrict__ flag) {
  if (*flag == 0) return;
  const size_t TOT8 = (IMN + SN) / 8;
  const size_t stride = (size_t)gridDim.x * blockDim.x;
  for (size_t g = (size_t)blockIdx.x * blockDim.x + threadIdx.x; g < TOT8; g += stride) {
    size_t base = g * 8;
    const u32* sp;
    u16* dst;
    if (base < IMN) { sp = (const u32*)im_in + base; dst = imB + base; }
    else            { sp = (const u32*)s_in + (base - IMN); dst = sB + (base - IMN); }
    u16 o[8];
#pragma unroll
    for (int e = 0; e < 8; ++e) o[e] = (u16)bf16_rne(sp[e]);
    *(uint4*)dst = *(const uint4*)o;
  }
}

// ---------------------------------------------------------------------------
// Kernel 0c: caption word norms. One wave per (c,w) row of 1024 bf16.
// ---------------------------------------------------------------------------
__global__ __launch_bounds__(64) void w1_k(const u16* __restrict__ s_orig,
                                           const u16* __restrict__ s_conv,
                                           const int* __restrict__ flag,
                                           float* __restrict__ w1) {
  const u16* s = *flag ? s_conv : s_orig;
  const int cw = blockIdx.x;           // 0..6399
  const int lane = threadIdx.x;
  const u16* sp = s + (size_t)cw * DD + lane * 16;
  uint4 A0 = *(const uint4*)sp;
  uint4 A1 = *(const uint4*)(sp + 8);
  float sum = 0.f;
  u32 uu[8] = {A0.x, A0.y, A0.z, A0.w, A1.x, A1.y, A1.z, A1.w};
#pragma unroll
  for (int e = 0; e < 8; ++e) {
    float2 f = bf16pair(uu[e]);
    sum += f.x * f.x + f.y * f.y;
  }
#pragma unroll
  for (int off = 32; off > 0; off >>= 1) sum += __shfl_down(sum, off);
  if (lane == 0) w1[cw] = sqrtf(sum);
}

// ---------------------------------------------------------------------------
// Kernel 1: per-image Gram G[i][r][r'] = <im[i,r], im[i,r']>. All 4 waves
// MFMA (K split 4-way), LDS cross-wave reduce at the end.
// ---------------------------------------------------------------------------
__global__ __launch_bounds__(256) void gram_k(const u16* __restrict__ im_orig,
                                              const u16* __restrict__ im_conv,
                                              const int* __restrict__ flag,
                                              float* __restrict__ G) {
  const u16* im = *flag ? im_conv : im_orig;
  __shared__ u16 ims[48 * 520];        // 49,920 B; reused as float scratch later
  const int b = blockIdx.x;
  const int t = threadIdx.x;
  const int lane = t & 63, wv = t >> 6;
  const int lm = lane & 15, q = lane >> 4;
  f32x4 acc[3][3] = {};

  for (int p = 0; p < 2; ++p) {
    const int kk = p * 512;
#pragma unroll
    for (int v = 0; v < 9; ++v) {
      int u = t + v * 256;          // 0..2303 = 36*64
      int row = u >> 6;
      int kloc = (u & 63) * 8;
      uint4 val = *(const uint4*)(im + (size_t)b * (RR * DD) + (size_t)row * DD + kk + kloc);
      *(uint4*)&ims[row * 520 + kloc] = val;
    }
    if (p == 0) {
#pragma unroll
      for (int v = 0; v < 4; ++v) {
        int u = t + v * 256;
        if (u < 780) {              // 12*520/8 = 780 uint4
          uint4 z; z.x = 0; z.y = 0; z.z = 0; z.w = 0;
          *(uint4*)&ims[36 * 520 + u * 8] = z;
        }
      }
    }
    __syncthreads();
#pragma unroll
    for (int kq = 0; kq < 4; ++kq) {
      const int ks = wv * 4 + kq;
      bf16x8 af[3];
#pragma unroll
      for (int mi = 0; mi < 3; ++mi)
        af[mi] = *(const bf16x8*)&ims[(mi * 16 + lm) * 520 + ks * 32 + q * 8];
#pragma unroll
      for (int mi = 0; mi < 3; ++mi)
#pragma unroll
        for (int ni = 0; ni < 3; ++ni)
          acc[mi][ni] = __builtin_amdgcn_mfma_f32_16x16x32_bf16(af[mi], af[ni], acc[mi][ni], 0, 0, 0);
    }
    __syncthreads();
  }
  float* red = (float*)ims;
  if (wv > 0) {
#pragma unroll
    for (int mi = 0; mi < 3; ++mi)
#pragma unroll
      for (int ni = 0; ni < 3; ++ni)
#pragma unroll
        for (int v = 0; v < 4; ++v) {
          int row = mi * 16 + q * 4 + v;
          int col = ni * 16 + lm;
          red[(wv - 1) * 2304 + row * 48 + col] = acc[mi][ni][v];
        }
  }
  __syncthreads();
  if (wv == 0) {
#pragma unroll
    for (int mi = 0; mi < 3; ++mi)
#pragma unroll
      for (int ni = 0; ni < 3; ++ni)
#pragma unroll
        for (int v = 0; v < 4; ++v) {
          int row = mi * 16 + q * 4 + v;
          int col = ni * 16 + lm;
          float r0 = acc[mi][ni][v] + red[row * 48 + col] +
                     red[2304 + row * 48 + col] + red[4608 + row * 48 + col];
          if (row < RR && col < RR)
            G[(size_t)b * (RR * RR) + row * RR + col] = r0;
        }
  }
}

// ---------------------------------------------------------------------------
// Kernel 2: raw[ir][cw] = sum_k im[ir][k] * s[cw][k]  (bf16 MFMA, bf16 out)
// M=4608, N=6400, K=1024. BM=BN=128, BK=32. grid (50, 36), 256 threads.
// ---------------------------------------------------------------------------
__global__ __launch_bounds__(256) void gemm_raw(const u16* __restrict__ A_orig,
                                                const u16* __restrict__ A_conv,
                                                const u16* __restrict__ B_orig,
                                                const u16* __restrict__ B_conv,
                                                const int* __restrict__ flag,
                                                u16* __restrict__ C) {
  const u16* A = *flag ? A_conv : A_orig;
  const u16* B = *flag ? B_conv : B_orig;
  __shared__ u16 As[128 * 32];
  __shared__ u16 Bs[128 * 32];
  const int t = threadIdx.x;
  const int col0 = blockIdx.x * 128;
  const int row0 = blockIdx.y * 128;
  const int lane = t & 63, wv = t >> 6;
  const int wm = wv >> 1, wn = wv & 1;
  const int lm = lane & 15, q = lane >> 4;
  f32x4 acc[4][4] = {};

  const int u0 = t, u1 = t + 256;
  const u16* a0 = A + (size_t)(row0 + (u0 >> 2)) * DD + (u0 & 3) * 8;
  const u16* a1 = A + (size_t)(row0 + (u1 >> 2)) * DD + (u1 & 3) * 8;
  const u16* b0 = B + (size_t)(col0 + (u0 >> 2)) * DD + (u0 & 3) * 8;
  const u16* b1 = B + (size_t)(col0 + (u1 >> 2)) * DD + (u1 & 3) * 8;

  for (int k0 = 0; k0 < DD; k0 += 32) {
    GLL16(a0 + k0, &As[u0 * 8]);
    GLL16(a1 + k0, &As[u1 * 8]);
    GLL16(b0 + k0, &Bs[u0 * 8]);
    GLL16(b1 + k0, &Bs[u1 * 8]);
    __syncthreads();
    bf16x8 af[4], bf[4];
#pragma unroll
    for (int mi = 0; mi < 4; ++mi)
      af[mi] = *(const bf16x8*)&As[(wm * 64 + mi * 16 + lm) * 32 + q * 8];
#pragma unroll
    for (int ni = 0; ni < 4; ++ni)
      bf[ni] = *(const bf16x8*)&Bs[(wn * 64 + ni * 16 + lm) * 32 + q * 8];
#pragma unroll
    for (int mi = 0; mi < 4; ++mi)
#pragma unroll
      for (int ni = 0; ni < 4; ++ni)
        acc[mi][ni] = __builtin_amdgcn_mfma_f32_16x16x32_bf16(af[mi], bf[ni], acc[mi][ni], 0, 0, 0);
    __syncthreads();
  }
#pragma unroll
  for (int mi = 0; mi < 4; ++mi)
#pragma unroll
    for (int ni = 0; ni < 4; ++ni)
#pragma unroll
      for (int v = 0; v < 4; ++v) {
        int rr = row0 + wm * 64 + mi * 16 + q * 4 + v;
        int cc = col0 + wn * 64 + ni * 16 + lm;
        C[(size_t)rr * LDC + cc] = (u16)bf16_rne(__float_as_uint(acc[mi][ni][v]));
      }
}

// ---------------------------------------------------------------------------
// Kernel 3: postproc, wave-per-(c,i) pair.
// Phase 1 (lanes=r): load bf16 raw row, leaky+mask, store UNNORMALIZED to aT,
// store nrm9 = 9/(||.||+eps). Phase 2-4 (lanes=w, uniform flow): scale on the
// fly, softmax over r in registers, w12 via inverse-leaky (no rnrm needed),
// qq = e'Ge via SYMMETRIC triangular loop with G in CONSTANT address space
// (uniform address -> s_load -> SGPR operands, no per-lane VMEM).
// ---------------------------------------------------------------------------
__global__ __launch_bounds__(256, 2) void postproc(const u16* __restrict__ raw,
                                                   const float* __restrict__ G,
                                                   const float* __restrict__ w1,
                                                   const int* __restrict__ s_l,
                                                   float* __restrict__ scores) {
  const int i = blockIdx.y;
  const int wv = threadIdx.x >> 6;
  const int c = blockIdx.x * 4 + wv;
  const int lane = threadIdx.x & 63;
  __shared__ float aT[4][WW * ATS];         // 4 * 7400 B
  __shared__ float nrm9_s[4][RR];           // 576 B
  const int L = s_l[c];

  // ---- phase 1: lanes = regions ----
  if (lane < RR) {
    const u16* rp = raw + (size_t)(i * RR + lane) * LDC + c * WW;
    float sum = 0.f;
#pragma unroll
    for (int j = 0; j < 25; ++j) {
      float2 v = bf16pair(((const u32*)rp)[j]);
      float x0 = v.x > 0.f ? v.x : 0.1f * v.x;
      float x1 = v.y > 0.f ? v.y : 0.1f * v.y;
      if (2 * j     >= L) x0 = 0.f;
      if (2 * j + 1 >= L) x1 = 0.f;
      aT[wv][(2 * j) * ATS + lane]     = x0;
      aT[wv][(2 * j + 1) * ATS + lane] = x1;
      sum += x0 * x0 + x1 * x1;
    }
    nrm9_s[wv][lane] = 9.0f / (sqrtf(sum) + 1e-8f);
  }
  __syncthreads();

  // ---- phases 2-4: uniform flow, lanes = words (clamped) ----
  const int wIdx = lane < WW ? lane : WW - 1;
  const float* row = &aT[wv][wIdx * ATS];
  cfloat* Gp = (cfloat*)(G + (size_t)i * (RR * RR));

  float x[RR];
  float m = -1e30f;
#pragma unroll
  for (int r = 0; r < RR; ++r) {
    x[r] = row[r];
    m = fmaxf(m, x[r] * nrm9_s[wv][r]);
  }
  float e[RR];
  float sum = 0.f, w12r = 0.f;
#pragma unroll
  for (int r = 0; r < RR; ++r) {
    float er = __expf(x[r] * nrm9_s[wv][r] - m);
    e[r] = er;
    sum += er;
    w12r += er * (x[r] > 0.f ? x[r] : 10.0f * x[r]);   // inverse-leaky: raw value
  }
  // qq = e'Ge, symmetric: qq = 2 * sum_r e_r*(0.5*G_rr*e_r + sum_{j>r} G_rj*e_j)
  float qq2 = 0.f;
#pragma unroll
  for (int r = 0; r < RR; ++r) {
    float h = 0.5f * Gp[r * RR + r] * e[r];
#pragma unroll
    for (int j = r + 1; j < RR; ++j)
      h += Gp[r * RR + j] * e[j];
    qq2 += e[r] * h;
  }
  float qq = 2.0f * qq2;
  float w1v = w1[c * WW + wIdx];
  float denom = fmaxf(w1v * sqrtf(fmaxf(qq, 0.f)), 1e-8f * sum);
  float rs = w12r / denom;
  float ew = (lane < L) ? __expf(6.0f * rs) : 0.f;
#pragma unroll
  for (int off = 32; off > 0; off >>= 1) ew += __shfl_down(ew, off);
  if (lane == 0) scores[i * NC + c] = logf(ew) * (1.0f / 6.0f);
}

// ---------------------------------------------------------------------------
// Kernel 4: hardest-negative contrastive loss over scores (128x128).
// ---------------------------------------------------------------------------
__global__ __launch_bounds__(128) void loss_k(const float* __restrict__ scores,
                                              u32* __restrict__ out) {
  __shared__ float diag[NI];
  __shared__ float red[NI];
  const int t = threadIdx.x;
  diag[t] = scores[t * NC + t];
  __syncthreads();
  const float di = diag[t];
  float rowmax = 0.f, colmax = 0.f;
  for (int k = 0; k < NC; ++k) {
    if (k != t) {
      float sr = scores[t * NC + k];
      rowmax = fmaxf(rowmax, fmaxf(0.2f + sr - di, 0.f));
      float sc = scores[k * NC + t];
      colmax = fmaxf(colmax, fmaxf(0.2f + sc - di, 0.f));
    }
  }
  red[t] = rowmax + colmax;
  __syncthreads();
  for (int st = 64; st > 0; st >>= 1) {
    if (t < st) red[t] += red[t + st];
    __syncthreads();
  }
  if (t == 0) {
    u32 b = bf16_rne(__float_as_uint(red[0]));
    out[0] = b | (b << 16);
  }
}

// ---------------------------------------------------------------------------
extern "C" void kernel_launch(void* const* d_in, const int* in_sizes, int n_in,
                              void* d_out, int out_size, void* d_ws, size_t ws_size,
                              hipStream_t stream) {
  const void* im_in = d_in[0];
  const void* s_in  = d_in[1];
  const int*  sl    = (const int*)d_in[2];

  char* ws = (char*)d_ws;
  u16*   imB    = (u16*)ws;                                  //  9,437,184 B
  u16*   sB     = (u16*)(ws + 9437184);                      // 13,107,200 B
  u16*   raw    = (u16*)(ws + 22544384);                     // 58,982,400 B (bf16)
  float* G      = (float*)(ws + 22544384 + 58982400);        //    663,552 B
  float* w1     = G + 128 * RR * RR;                         //     25,600 B
  float* scores = w1 + NC * WW;                              //     65,536 B
  int*   flag   = (int*)(scores + NI * NC);

  detect_dtype<<<dim3(1), dim3(256), 0, stream>>>((const u16*)im_in, flag);
  convert_in<<<dim3(2048), dim3(256), 0, stream>>>(im_in, s_in, imB, sB, flag);
  w1_k<<<dim3(NC * WW), dim3(64), 0, stream>>>((const u16*)s_in, sB, flag, w1);
  gram_k<<<dim3(128), dim3(256), 0, stream>>>((const u16*)im_in, imB, flag, G);
  gemm_raw<<<dim3(50, 36), dim3(256), 0, stream>>>((const u16*)im_in, imB,
                                                   (const u16*)s_in, sB, flag, raw);
  postproc<<<dim3(32, 128), dim3(256), 0, stream>>>(raw, G, w1, sl, scores);
  loss_k<<<dim3(1), dim3(128), 0, stream>>>(scores, (u32*)d_out);
}

// Round 6
// 277.284 us; speedup vs baseline: 2.0118x; 1.0281x over previous
//
#include <hip/hip_runtime.h>
#include <hip/hip_bf16.h>
#include <cstdint>

using u16 = unsigned short;
using u32 = unsigned int;
using bf16x8 = __attribute__((ext_vector_type(8))) short;
using f32x4  = __attribute__((ext_vector_type(4))) float;

// Problem constants
#define NI 128
#define NC 128
#define RR 36
#define WW 50
#define DD 1024
#define LDC 6400   // = NC*WW
#define ATS 37     // aT row stride (floats), conflict-free
#define IMN ((size_t)NI * RR * DD)   // 4,718,592
#define SN  ((size_t)NC * WW * DD)   // 6,553,600

#define GLL16(g, l) __builtin_amdgcn_global_load_lds(                        \
    (const __attribute__((address_space(1))) void*)(g),                      \
    (__attribute__((address_space(3))) void*)(l), 16, 0, 0)

// constant-address-space float: uniform loads select s_load (SGPR data)
typedef const __attribute__((address_space(4))) float cfloat;

__device__ __forceinline__ float2 bf16pair(u32 u) {
  float2 f;
  f.x = __uint_as_float(u << 16);
  f.y = __uint_as_float(u & 0xffff0000u);
  return f;
}

__device__ __forceinline__ u32 bf16_rne(u32 x) {
  return (x + 0x7FFFu + ((x >> 16) & 1u)) >> 16;
}

// ---------------------------------------------------------------------------
// Kernel 0: convert + embedded dtype sniff. Each block sniffs the first 4096
// u16 of im (bf16 N(0,1) never has exponent bits >= 0xC0; fp32 mantissa
// halves hit it ~25% of the time). Block 0 publishes the flag for the
// downstream kernels; all blocks agree (same data). Early-out when bf16.
// ---------------------------------------------------------------------------
__global__ __launch_bounds__(256) void convert_in(const void* __restrict__ im_in,
                                                  const void* __restrict__ s_in,
                                                  u16* __restrict__ imB,
                                                  u16* __restrict__ sB,
                                                  int* __restrict__ flag) {
  __shared__ int cnt;
  if (threadIdx.x == 0) cnt = 0;
  __syncthreads();
  const u16* imu = (const u16*)im_in;
  int local = 0;
#pragma unroll
  for (int v = 0; v < 16; ++v) {
    u16 u = imu[threadIdx.x * 16 + v];
    if (((u >> 7) & 0xFF) >= 0xC0) local++;
  }
  if (local) atomicAdd(&cnt, local);
  __syncthreads();
  const int f = (cnt > 4) ? 1 : 0;
  if (blockIdx.x == 0 && threadIdx.x == 0) *flag = f;
  if (!f) return;

  const size_t TOT8 = (IMN + SN) / 8;
  const size_t stride = (size_t)gridDim.x * blockDim.x;
  for (size_t g = (size_t)blockIdx.x * blockDim.x + threadIdx.x; g < TOT8; g += stride) {
    size_t base = g * 8;
    const u32* sp;
    u16* dst;
    if (base < IMN) { sp = (const u32*)im_in + base; dst = imB + base; }
    else            { sp = (const u32*)s_in + (base - IMN); dst = sB + (base - IMN); }
    u16 o[8];
#pragma unroll
    for (int e = 0; e < 8; ++e) o[e] = (u16)bf16_rne(sp[e]);
    *(uint4*)dst = *(const uint4*)o;
  }
}

// ---------------------------------------------------------------------------
// Kernel 1: per-image Gram G[i][r][r'] (MFMA, all 4 waves, K split 4-way)
// + caption word norms w1[b][w] folded in (all 4 waves, 12-13 rows each).
// One block per b = i = c.
// ---------------------------------------------------------------------------
__global__ __launch_bounds__(256) void gram_w1(const u16* __restrict__ im_orig,
                                               const u16* __restrict__ im_conv,
                                               const u16* __restrict__ s_orig,
                                               const u16* __restrict__ s_conv,
                                               const int* __restrict__ flag,
                                               float* __restrict__ G,
                                               float* __restrict__ w1) {
  const u16* im = *flag ? im_conv : im_orig;
  const u16* s  = *flag ? s_conv : s_orig;
  __shared__ u16 ims[48 * 520];        // 49,920 B; reused as float scratch later
  const int b = blockIdx.x;
  const int t = threadIdx.x;
  const int lane = t & 63, wv = t >> 6;
  const int lm = lane & 15, q = lane >> 4;
  f32x4 acc[3][3] = {};

  for (int p = 0; p < 2; ++p) {
    const int kk = p * 512;
#pragma unroll
    for (int v = 0; v < 9; ++v) {
      int u = t + v * 256;          // 0..2303 = 36*64
      int row = u >> 6;
      int kloc = (u & 63) * 8;
      uint4 val = *(const uint4*)(im + (size_t)b * (RR * DD) + (size_t)row * DD + kk + kloc);
      *(uint4*)&ims[row * 520 + kloc] = val;
    }
    if (p == 0) {
#pragma unroll
      for (int v = 0; v < 4; ++v) {
        int u = t + v * 256;
        if (u < 780) {              // 12*520/8 = 780 uint4
          uint4 z; z.x = 0; z.y = 0; z.z = 0; z.w = 0;
          *(uint4*)&ims[36 * 520 + u * 8] = z;
        }
      }
    }
    __syncthreads();
#pragma unroll
    for (int kq = 0; kq < 4; ++kq) {
      const int ks = wv * 4 + kq;
      bf16x8 af[3];
#pragma unroll
      for (int mi = 0; mi < 3; ++mi)
        af[mi] = *(const bf16x8*)&ims[(mi * 16 + lm) * 520 + ks * 32 + q * 8];
#pragma unroll
      for (int mi = 0; mi < 3; ++mi)
#pragma unroll
        for (int ni = 0; ni < 3; ++ni)
          acc[mi][ni] = __builtin_amdgcn_mfma_f32_16x16x32_bf16(af[mi], af[ni], acc[mi][ni], 0, 0, 0);
    }
    __syncthreads();
  }
  float* red = (float*)ims;
  if (wv > 0) {
#pragma unroll
    for (int mi = 0; mi < 3; ++mi)
#pragma unroll
      for (int ni = 0; ni < 3; ++ni)
#pragma unroll
        for (int v = 0; v < 4; ++v) {
          int row = mi * 16 + q * 4 + v;
          int col = ni * 16 + lm;
          red[(wv - 1) * 2304 + row * 48 + col] = acc[mi][ni][v];
        }
  }
  __syncthreads();
  if (wv == 0) {
#pragma unroll
    for (int mi = 0; mi < 3; ++mi)
#pragma unroll
      for (int ni = 0; ni < 3; ++ni)
#pragma unroll
        for (int v = 0; v < 4; ++v) {
          int row = mi * 16 + q * 4 + v;
          int col = ni * 16 + lm;
          float r0 = acc[mi][ni][v] + red[row * 48 + col] +
                     red[2304 + row * 48 + col] + red[4608 + row * 48 + col];
          if (row < RR && col < RR)
            G[(size_t)b * (RR * RR) + row * RR + col] = r0;
        }
  }
  // w1 rows for caption b (no LDS dependency)
  const u16* sc = s + (size_t)b * WW * DD;
  for (int w = wv; w < WW; w += 4) {
    const u16* sp = sc + (size_t)w * DD + lane * 16;
    uint4 A0 = *(const uint4*)sp;
    uint4 A1 = *(const uint4*)(sp + 8);
    float sum = 0.f;
    u32 uu[8] = {A0.x, A0.y, A0.z, A0.w, A1.x, A1.y, A1.z, A1.w};
#pragma unroll
    for (int e = 0; e < 8; ++e) {
      float2 f = bf16pair(uu[e]);
      sum += f.x * f.x + f.y * f.y;
    }
#pragma unroll
    for (int off = 32; off > 0; off >>= 1) sum += __shfl_down(sum, off);
    if (lane == 0) w1[b * WW + w] = sqrtf(sum);
  }
}

// ---------------------------------------------------------------------------
// Kernel 2: raw[ir][cw] = sum_k im[ir][k] * s[cw][k]  (bf16 MFMA, bf16 out)
// M=4608, N=6400, K=1024. BM=BN=128, BK=64, grid (50,36), 256 threads.
// XOR-swizzled LDS: logical k-chunk c of row r lives at physical chunk
// p = c ^ (r&7). Staging inverts the swizzle on the GLOBAL side (free);
// ds_read start banks spread across all 8 groups -> conflict-free b128.
// ---------------------------------------------------------------------------
__global__ __launch_bounds__(256) void gemm_raw(const u16* __restrict__ A_orig,
                                                const u16* __restrict__ A_conv,
                                                const u16* __restrict__ B_orig,
                                                const u16* __restrict__ B_conv,
                                                const int* __restrict__ flag,
                                                u16* __restrict__ C) {
  const u16* A = *flag ? A_conv : A_orig;
  const u16* B = *flag ? B_conv : B_orig;
  __shared__ u16 As[128 * 64];   // 16 KB
  __shared__ u16 Bs[128 * 64];   // 16 KB
  const int t = threadIdx.x;
  const int col0 = blockIdx.x * 128;
  const int row0 = blockIdx.y * 128;
  const int lane = t & 63, wv = t >> 6;
  const int wm = wv >> 1, wn = wv & 1;
  const int lm = lane & 15, q = lane >> 4;
  f32x4 acc[4][4] = {};

  // staging pointers with inverse-swizzled k-chunk
  const u16* ap[4];
  const u16* bp[4];
#pragma unroll
  for (int v = 0; v < 4; ++v) {
    int u = t + v * 256;
    int row = u >> 3;
    int c = (u & 7) ^ (row & 7);
    ap[v] = A + (size_t)(row0 + row) * DD + c * 8;
    bp[v] = B + (size_t)(col0 + row) * DD + c * 8;
  }

  for (int k0 = 0; k0 < DD; k0 += 64) {
#pragma unroll
    for (int v = 0; v < 4; ++v) GLL16(ap[v] + k0, &As[(t + v * 256) * 8]);
#pragma unroll
    for (int v = 0; v < 4; ++v) GLL16(bp[v] + k0, &Bs[(t + v * 256) * 8]);
    __syncthreads();
#pragma unroll
    for (int ks = 0; ks < 2; ++ks) {
      bf16x8 af[4], bf[4];
      const int pch = (ks * 4 + q) ^ (lm & 7);   // physical chunk
#pragma unroll
      for (int mi = 0; mi < 4; ++mi)
        af[mi] = *(const bf16x8*)&As[(wm * 64 + mi * 16 + lm) * 64 + pch * 8];
#pragma unroll
      for (int ni = 0; ni < 4; ++ni)
        bf[ni] = *(const bf16x8*)&Bs[(wn * 64 + ni * 16 + lm) * 64 + pch * 8];
#pragma unroll
      for (int mi = 0; mi < 4; ++mi)
#pragma unroll
        for (int ni = 0; ni < 4; ++ni)
          acc[mi][ni] = __builtin_amdgcn_mfma_f32_16x16x32_bf16(af[mi], bf[ni], acc[mi][ni], 0, 0, 0);
    }
    __syncthreads();
  }
#pragma unroll
  for (int mi = 0; mi < 4; ++mi)
#pragma unroll
    for (int ni = 0; ni < 4; ++ni)
#pragma unroll
      for (int v = 0; v < 4; ++v) {
        int rr = row0 + wm * 64 + mi * 16 + q * 4 + v;
        int cc = col0 + wn * 64 + ni * 16 + lm;
        C[(size_t)rr * LDC + cc] = (u16)bf16_rne(__float_as_uint(acc[mi][ni][v]));
      }
}

// ---------------------------------------------------------------------------
// Kernel 3: postproc, wave-per-(c,i) pair (unchanged from round 5 — the
// AS(4) scalar-G path measured a large win).
// ---------------------------------------------------------------------------
__global__ __launch_bounds__(256, 2) void postproc(const u16* __restrict__ raw,
                                                   const float* __restrict__ G,
                                                   const float* __restrict__ w1,
                                                   const int* __restrict__ s_l,
                                                   float* __restrict__ scores) {
  const int i = blockIdx.y;
  const int wv = threadIdx.x >> 6;
  const int c = blockIdx.x * 4 + wv;
  const int lane = threadIdx.x & 63;
  __shared__ float aT[4][WW * ATS];         // 4 * 7400 B
  __shared__ float nrm9_s[4][RR];           // 576 B
  const int L = s_l[c];

  // ---- phase 1: lanes = regions ----
  if (lane < RR) {
    const u16* rp = raw + (size_t)(i * RR + lane) * LDC + c * WW;
    float sum = 0.f;
#pragma unroll
    for (int j = 0; j < 25; ++j) {
      float2 v = bf16pair(((const u32*)rp)[j]);
      float x0 = v.x > 0.f ? v.x : 0.1f * v.x;
      float x1 = v.y > 0.f ? v.y : 0.1f * v.y;
      if (2 * j     >= L) x0 = 0.f;
      if (2 * j + 1 >= L) x1 = 0.f;
      aT[wv][(2 * j) * ATS + lane]     = x0;
      aT[wv][(2 * j + 1) * ATS + lane] = x1;
      sum += x0 * x0 + x1 * x1;
    }
    nrm9_s[wv][lane] = 9.0f / (sqrtf(sum) + 1e-8f);
  }
  __syncthreads();

  // ---- phases 2-4: uniform flow, lanes = words (clamped) ----
  const int wIdx = lane < WW ? lane : WW - 1;
  const float* row = &aT[wv][wIdx * ATS];
  cfloat* Gp = (cfloat*)(G + (size_t)i * (RR * RR));

  float x[RR];
  float m = -1e30f;
#pragma unroll
  for (int r = 0; r < RR; ++r) {
    x[r] = row[r];
    m = fmaxf(m, x[r] * nrm9_s[wv][r]);
  }
  float e[RR];
  float sum = 0.f, w12r = 0.f;
#pragma unroll
  for (int r = 0; r < RR; ++r) {
    float er = __expf(x[r] * nrm9_s[wv][r] - m);
    e[r] = er;
    sum += er;
    w12r += er * (x[r] > 0.f ? x[r] : 10.0f * x[r]);   // inverse-leaky: raw value
  }
  float qq2 = 0.f;
#pragma unroll
  for (int r = 0; r < RR; ++r) {
    float h = 0.5f * Gp[r * RR + r] * e[r];
#pragma unroll
    for (int j = r + 1; j < RR; ++j)
      h += Gp[r * RR + j] * e[j];
    qq2 += e[r] * h;
  }
  float qq = 2.0f * qq2;
  float w1v = w1[c * WW + wIdx];
  float denom = fmaxf(w1v * sqrtf(fmaxf(qq, 0.f)), 1e-8f * sum);
  float rs = w12r / denom;
  float ew = (lane < L) ? __expf(6.0f * rs) : 0.f;
#pragma unroll
  for (int off = 32; off > 0; off >>= 1) ew += __shfl_down(ew, off);
  if (lane == 0) scores[i * NC + c] = logf(ew) * (1.0f / 6.0f);
}

// ---------------------------------------------------------------------------
// Kernel 4: hardest-negative contrastive loss over scores (128x128).
// ---------------------------------------------------------------------------
__global__ __launch_bounds__(128) void loss_k(const float* __restrict__ scores,
                                              u32* __restrict__ out) {
  __shared__ float diag[NI];
  __shared__ float red[NI];
  const int t = threadIdx.x;
  diag[t] = scores[t * NC + t];
  __syncthreads();
  const float di = diag[t];
  float rowmax = 0.f, colmax = 0.f;
  for (int k = 0; k < NC; ++k) {
    if (k != t) {
      float sr = scores[t * NC + k];
      rowmax = fmaxf(rowmax, fmaxf(0.2f + sr - di, 0.f));
      float sc = scores[k * NC + t];
      colmax = fmaxf(colmax, fmaxf(0.2f + sc - di, 0.f));
    }
  }
  red[t] = rowmax + colmax;
  __syncthreads();
  for (int st = 64; st > 0; st >>= 1) {
    if (t < st) red[t] += red[t + st];
    __syncthreads();
  }
  if (t == 0) {
    u32 b = bf16_rne(__float_as_uint(red[0]));
    out[0] = b | (b << 16);
  }
}

// ---------------------------------------------------------------------------
extern "C" void kernel_launch(void* const* d_in, const int* in_sizes, int n_in,
                              void* d_out, int out_size, void* d_ws, size_t ws_size,
                              hipStream_t stream) {
  const void* im_in = d_in[0];
  const void* s_in  = d_in[1];
  const int*  sl    = (const int*)d_in[2];

  char* ws = (char*)d_ws;
  u16*   imB    = (u16*)ws;                                  //  9,437,184 B
  u16*   sB     = (u16*)(ws + 9437184);                      // 13,107,200 B
  u16*   raw    = (u16*)(ws + 22544384);                     // 58,982,400 B (bf16)
  float* G      = (float*)(ws + 22544384 + 58982400);        //    663,552 B
  float* w1     = G + 128 * RR * RR;                         //     25,600 B
  float* scores = w1 + NC * WW;                              //     65,536 B
  int*   flag   = (int*)(scores + NI * NC);

  convert_in<<<dim3(2048), dim3(256), 0, stream>>>(im_in, s_in, imB, sB, flag);
  gram_w1<<<dim3(128), dim3(256), 0, stream>>>((const u16*)im_in, imB,
                                               (const u16*)s_in, sB, flag, G, w1);
  gemm_raw<<<dim3(50, 36), dim3(256), 0, stream>>>((const u16*)im_in, imB,
                                                   (const u16*)s_in, sB, flag, raw);
  postproc<<<dim3(32, 128), dim3(256), 0, stream>>>(raw, G, w1, sl, scores);
  loss_k<<<dim3(1), dim3(128), 0, stream>>>(scores, (u32*)d_out);
}